// Round 1
// 395.382 us; speedup vs baseline: 1.0459x; 1.0459x over previous
//
#include <hip/hip_runtime.h>
#include <hip/hip_bf16.h>

#define IDIM 1771
#define NF 64
#define NG 512

constexpr int OFFS[12] = {0, 1, 10, 35, 84, 165, 286, 455, 680, 969, 1330, 1771};

typedef float f32x4 __attribute__((ext_vector_type(4)));
typedef float f32x2 __attribute__((ext_vector_type(2)));
typedef __bf16 bf16x2 __attribute__((ext_vector_type(2)));
typedef __bf16 bf16x8 __attribute__((ext_vector_type(8)));

__device__ __forceinline__ void gl_lds16(const void* g, void* l) {
    __builtin_amdgcn_global_load_lds((const __attribute__((address_space(1))) void*)g,
                                     (__attribute__((address_space(3))) void*)l, 16, 0, 0);
}

// ---------------------------------------------------------------------------
// Fused prep + repack_x (independent work, one launch):
//  blk 0..223   : transpose D (512,1771) fp32 -> Dt (1771,512) bf16
//  blk 224..287 : transpose-cast w[i][o][n] fp32 -> wb[o][i][n] bf16
//  blk 288..3103: repack x -> A_l[256d][64d] bf16, row r=b*d+m, col k=u*64+i
//                 phase2 now emits bf16x8 (16B) stores: 8x fewer store instrs.
// ---------------------------------------------------------------------------
__global__ __launch_bounds__(256) void prep_repack_kernel(const float* __restrict__ D,
                                                          const float* __restrict__ w,
                                                          const float* __restrict__ x,
                                                          __bf16* __restrict__ Dt,
                                                          __bf16* __restrict__ wb,
                                                          __hip_bfloat16* __restrict__ A) {
    __shared__ alignas(16) char smem[16640];
    const int blk = blockIdx.x;
    const int t = threadIdx.x;
    const int lane = t & 63, grp = t >> 6;

    if (blk < 224) {
        // D transpose
        float (*T)[65] = (float (*)[65])smem;
        const int ct = blk >> 3, nt = blk & 7;
        const int c0 = ct * 64, n0 = nt * 64;
        for (int nn = grp; nn < 64; nn += 4) {
            int c = c0 + lane;
            T[nn][lane] = (c < IDIM) ? D[(n0 + nn) * IDIM + c] : 0.0f;
        }
        __syncthreads();
        for (int cc = grp; cc < 64; cc += 4) {
            int c = c0 + cc;
            if (c < IDIM) Dt[c * NG + n0 + lane] = (__bf16)T[lane][cc];
        }
    } else if (blk < 288) {
        // w transpose-cast: wb[o][i][n] = bf16(w[i][o][n])
        const int o = blk - 224;
#pragma unroll 4
        for (int ii = 0; ii < 64; ++ii) {
            f32x2 v = *(const f32x2*)&w[((size_t)(ii * 64 + o)) * NG + t * 2];
            bf16x2 ov;
            ov.x = (__bf16)v.x;
            ov.y = (__bf16)v.y;
            *(bf16x2*)&wb[((size_t)(o * 64 + ii)) * NG + t * 2] = ov;
        }
    } else {
        // repack x: A[m][u*64+i] = bf16(x[b][i][off+u*d+m])
        const int idx = blk - 288;
        const int l = idx >> 8;        // 0..10
        const int b = idx & 255;       // 0..255
        const int d = 2 * l + 1, off = OFFS[l], csq = d * d, Kp = 64 * d;
        __bf16 (*T)[66] = (__bf16 (*)[66])smem;  // [i=64][c=66 padded]
        const float* xb = x + (size_t)b * NF * IDIM + off;
        __bf16* Ab = (__bf16*)(A + (size_t)16384 * off + (size_t)b * d * Kp);

        for (int c0 = 0; c0 < csq; c0 += 64) {
            // phase 1: coalesced f32 reads, transposed-in-name LDS fill T[i][c]
            for (int ii = grp; ii < 64; ii += 4) {
                int c = c0 + lane;
                float v = (c < csq) ? xb[ii * IDIM + c] : 0.0f;
                T[ii][lane] = (__bf16)v;
            }
            __syncthreads();
            // phase 2: per-thread gather 8 i's for one c -> one 16B store
#pragma unroll
            for (int s = 0; s < 2; ++s) {
                int idx2 = s * 256 + t;
                int c_loc = idx2 >> 3, i0 = (idx2 & 7) * 8;
                int c = c0 + c_loc;
                if (c < csq) {
                    int u = (unsigned)c / (unsigned)d;
                    int m = c - u * d;
                    bf16x8 v;
#pragma unroll
                    for (int j = 0; j < 8; ++j) v[j] = T[i0 + j][c_loc];
                    *(bf16x8*)(Ab + (size_t)m * Kp + u * 64 + i0) = v;
                }
            }
            __syncthreads();
        }
    }
}

// ---------------------------------------------------------------------------
// psi GEMM (MFMA): psi[c][io'] = (1/sqrt512) * sum_n Dt[c][n] * wb[io'][n]
// Pipelined: double-buffered LDS, STAGE(next) issued before compute(cur),
// single counted wait + raw barrier per K-step (no per-step vmcnt(0) drain
// blocking the prefetch -- the wait lands AFTER the MFMA cluster).
// ---------------------------------------------------------------------------
__global__ __launch_bounds__(256) void psi_mfma_kernel(const __bf16* __restrict__ Dt,
                                                       const __bf16* __restrict__ wb,
                                                       __bf16* __restrict__ Bm) {
    __shared__ alignas(16) __bf16 S[4][4096];  // As0, Bs0, As1, Bs1

    const int t = threadIdx.x, w = t >> 6, ln = t & 63;
    const int row0 = blockIdx.x * 128;  // c
    const int col0 = blockIdx.y * 128;  // io'

    const __bf16* gp[4];
    __bf16* lp[4];
#pragma unroll
    for (int q = 0; q < 4; ++q) {
        int chunk = w * 4 + q;
        bool isA = chunk < 8;
        int j = chunk & 7;
        int r16 = j * 16 + (ln >> 2);
        int g = isA ? (row0 + r16 < IDIM ? row0 + r16 : IDIM - 1) : (col0 + r16);
        gp[q] = (isA ? Dt : wb) + (size_t)g * NG + (ln & 3) * 8;
        lp[q] = S[isA ? 0 : 1] + j * 512;
    }

    f32x4 acc[4][4];
    f32x4 zero = {0.0f, 0.0f, 0.0f, 0.0f};
#pragma unroll
    for (int i = 0; i < 4; ++i)
#pragma unroll
        for (int j = 0; j < 4; ++j) acc[i][j] = zero;

    const int wr = (w >> 1) * 64, wc = (w & 1) * 64;
    const int fr = ln & 15, kh = ln >> 4;

    // prologue: stage buf0, drain, sync
#pragma unroll
    for (int q = 0; q < 4; ++q) { gl_lds16(gp[q], lp[q]); gp[q] += 32; }
    asm volatile("s_waitcnt vmcnt(0)" ::: "memory");
    __builtin_amdgcn_s_barrier();
    __builtin_amdgcn_sched_barrier(0);

    int cur = 0;
    for (int kt = 0; kt < NG; kt += 32) {
        if (kt + 32 < NG) {
#pragma unroll
            for (int q = 0; q < 4; ++q) {
                gl_lds16(gp[q], lp[q] + (cur ^ 1) * 8192);
                gp[q] += 32;
            }
        }
        const __bf16* As_ = S[cur * 2];
        const __bf16* Bs_ = S[cur * 2 + 1];
        bf16x8 af[4], bfr[4];
#pragma unroll
        for (int mt = 0; mt < 4; ++mt)
            af[mt] = *(const bf16x8*)&As_[(wr + mt * 16 + fr) * 32 + kh * 8];
#pragma unroll
        for (int nt = 0; nt < 4; ++nt)
            bfr[nt] = *(const bf16x8*)&Bs_[(wc + nt * 16 + fr) * 32 + kh * 8];
#pragma unroll
        for (int mt = 0; mt < 4; ++mt)
#pragma unroll
            for (int nt = 0; nt < 4; ++nt)
                acc[mt][nt] = __builtin_amdgcn_mfma_f32_16x16x32_bf16(af[mt], bfr[nt],
                                                                      acc[mt][nt], 0, 0, 0);
        asm volatile("s_waitcnt vmcnt(0)" ::: "memory");  // next-buf loads landed
        __builtin_amdgcn_s_barrier();                     // everyone done reading cur
        __builtin_amdgcn_sched_barrier(0);
        cur ^= 1;
    }

    const float s = 0.04419417382415922f;  // 1/sqrt(512)
    const int o = (col0 + wc) >> 6;        // wave-uniform
#pragma unroll
    for (int mt = 0; mt < 4; ++mt) {
#pragma unroll
        for (int e = 0; e < 4; ++e) {
            int c = row0 + wr + mt * 16 + kh * 4 + e;
            if (c < IDIM) {
                int l = 0;
#pragma unroll
                for (int ll = 1; ll < 11; ++ll)
                    if (c >= OFFS[ll]) l = ll;
                int d = 2 * l + 1, off = OFFS[l];
                int rem = c - off;
                int u = (unsigned)rem / (unsigned)d;
                int v = rem - u * d;
                __bf16* bb = Bm + (size_t)4096 * off + (size_t)(o * d + v) * (64 * d) + u * 64;
#pragma unroll
                for (int nt = 0; nt < 4; ++nt) {
                    int i = nt * 16 + fr;  // consecutive across 16-lane group
                    bb[i] = (__bf16)(acc[mt][nt][e] * s);
                }
            }
        }
    }
}

// ---------------------------------------------------------------------------
// Merged stage-2 GEMM, XCD-swizzled, now pipelined (double-buffered LDS,
// prefetch-before-compute, one barrier per K-step). Epilogue unchanged.
// ---------------------------------------------------------------------------
__global__ __launch_bounds__(256) void so3_gemm_all(const __bf16* __restrict__ A,
                                                    const __bf16* __restrict__ Bm,
                                                    float* __restrict__ out) {
    const int bid = blockIdx.x;
    const int v_ = (bid & 7) * 237 + (bid >> 3);  // grid 1896 = 8*237
    if (v_ >= 1892) return;

    int l = 10, base = 0;
    if (v_ >= 462)  { l = 9; base = 462; }
    if (v_ >= 842)  { l = 8; base = 842; }
    if (v_ >= 1148) { l = 7; base = 1148; }
    if (v_ >= 1388) { l = 6; base = 1388; }
    if (v_ >= 1570) { l = 5; base = 1570; }
    if (v_ >= 1702) { l = 4; base = 1702; }
    if (v_ >= 1792) { l = 3; base = 1792; }
    if (v_ >= 1848) { l = 2; base = 1848; }
    if (v_ >= 1878) { l = 1; base = 1878; }
    if (v_ >= 1890) { l = 0; base = 1890; }

    const int d = 2 * l + 1;
    const int off = OFFS[l];
    const int Np = 64 * d, Kp = 64 * d;
    const int ntiles = l + 1;
    const int rel = v_ - base;
    const int bx = (unsigned)rel / (unsigned)ntiles;
    const int by = rel - bx * ntiles;
    const int row0 = bx * 128, col0 = by * 128;

    constexpr float ALPHA[11] = {0.125f, 0.07216878f, 0.05590170f, 0.04724556f,
                                 0.04166667f, 0.03768892f, 0.03466879f, 0.03227486f,
                                 0.03031695f, 0.02867697f, 0.02727724f};

    __shared__ alignas(16) __bf16 S[4][4096];  // As0, Bs0, As1, Bs1

    const int t = threadIdx.x, w = t >> 6, ln = t & 63;

    const __bf16* Abase = A + (size_t)16384 * off;
    const __bf16* Bbase = Bm + (size_t)4096 * off;

    const __bf16* gp[4];
    __bf16* lp[4];
#pragma unroll
    for (int q = 0; q < 4; ++q) {
        int chunk = w * 4 + q;
        bool isA = chunk < 8;
        int j = chunk & 7;
        int r16 = j * 16 + (ln >> 2);
        int g = isA ? (row0 + r16) : (col0 + r16 < Np ? col0 + r16 : Np - 1);
        gp[q] = (isA ? Abase : Bbase) + (size_t)g * Kp + (ln & 3) * 8;
        lp[q] = S[isA ? 0 : 1] + j * 512;
    }

    f32x4 acc[4][4];
    f32x4 zero = {0.0f, 0.0f, 0.0f, 0.0f};
#pragma unroll
    for (int i = 0; i < 4; ++i)
#pragma unroll
        for (int j = 0; j < 4; ++j) acc[i][j] = zero;

    const int wr = (w >> 1) * 64, wc = (w & 1) * 64;
    const int fr = ln & 15, kh = ln >> 4;

    // prologue: stage buf0, drain, sync
#pragma unroll
    for (int q = 0; q < 4; ++q) { gl_lds16(gp[q], lp[q]); gp[q] += 32; }
    asm volatile("s_waitcnt vmcnt(0)" ::: "memory");
    __builtin_amdgcn_s_barrier();
    __builtin_amdgcn_sched_barrier(0);

    int cur = 0;
    for (int kt = 0; kt < Kp; kt += 32) {
        if (kt + 32 < Kp) {
#pragma unroll
            for (int q = 0; q < 4; ++q) {
                gl_lds16(gp[q], lp[q] + (cur ^ 1) * 8192);
                gp[q] += 32;
            }
        }
        const __bf16* As_ = S[cur * 2];
        const __bf16* Bs_ = S[cur * 2 + 1];
        bf16x8 af[4], bfr[4];
#pragma unroll
        for (int mt = 0; mt < 4; ++mt)
            af[mt] = *(const bf16x8*)&As_[(wr + mt * 16 + fr) * 32 + kh * 8];
#pragma unroll
        for (int nt = 0; nt < 4; ++nt)
            bfr[nt] = *(const bf16x8*)&Bs_[(wc + nt * 16 + fr) * 32 + kh * 8];
#pragma unroll
        for (int mt = 0; mt < 4; ++mt)
#pragma unroll
            for (int nt = 0; nt < 4; ++nt)
                acc[mt][nt] = __builtin_amdgcn_mfma_f32_16x16x32_bf16(af[mt], bfr[nt],
                                                                      acc[mt][nt], 0, 0, 0);
        asm volatile("s_waitcnt vmcnt(0)" ::: "memory");  // next-buf loads landed
        __builtin_amdgcn_s_barrier();                     // everyone done reading cur
        __builtin_amdgcn_sched_barrier(0);
        cur ^= 1;
    }

    // ---- epilogue: per-wave LDS reorder so stores run contiguous along m ----
    __syncthreads();  // all waves done with LDS before we reuse it
    float* Tw = (float*)S + w * 256;  // 16x16 f32 per wave (1KB)
    const float alpha = ALPHA[l];

#pragma unroll
    for (int mt = 0; mt < 4; ++mt) {
        // this lane's store row: r = row0+wr+mt*16+fr (contiguous across fr)
        int r = row0 + wr + mt * 16 + fr;
        int b = (unsigned)r / (unsigned)d;
        int m = r - b * d;
        float* ob = out + (size_t)b * NF * IDIM + off + m;
#pragma unroll
        for (int nt = 0; nt < 4; ++nt) {
            // write C subtile (row=kh*4+e, col=fr) into Tw[row][col]
#pragma unroll
            for (int e = 0; e < 4; ++e) Tw[(kh * 4 + e) * 16 + fr] = acc[mt][nt][e];
            // read back transposed: lane handles (row=fr, cols kh*4..kh*4+3)
            f32x4 vals = *(const f32x4*)&Tw[fr * 16 + kh * 4];
            int qb = col0 + wc + nt * 16 + kh * 4;
            int o = (unsigned)qb / (unsigned)d;
            int vv = qb - o * d;
#pragma unroll
            for (int j = 0; j < 4; ++j) {
                if (qb + j < Np) ob[o * IDIM + vv * d] = alpha * vals[j];
                ++vv;
                if (vv == d) { vv = 0; ++o; }
            }
        }
    }
}

// ---------------------------------------------------------------------------
extern "C" void kernel_launch(void* const* d_in, const int* in_sizes, int n_in,
                              void* d_out, int out_size, void* d_ws, size_t ws_size,
                              hipStream_t stream) {
    const float* x = (const float*)d_in[0];   // (256, 64, 1771)
    const float* D = (const float*)d_in[1];   // (512, 1771)
    const float* w = (const float*)d_in[2];   // (64, 64, 512)
    float* out = (float*)d_out;               // (256, 64, 1771)

    char* ws = (char*)d_ws;
    const size_t DT_BYTES = (size_t)IDIM * NG * 2;        // 1,813,504
    const size_t WB_BYTES = (size_t)4096 * NG * 2;        // 4,194,304
    const size_t A_BYTES = (size_t)16384 * IDIM * 2;      // 58,032,128

    __bf16* Dt = (__bf16*)ws;
    __bf16* wb = (__bf16*)(ws + DT_BYTES);
    __hip_bfloat16* A = (__hip_bfloat16*)(ws + DT_BYTES + WB_BYTES);
    __bf16* Bm = (__bf16*)(ws + DT_BYTES + WB_BYTES + A_BYTES);

    prep_repack_kernel<<<3104, 256, 0, stream>>>(D, w, x, Dt, wb, A);
    psi_mfma_kernel<<<dim3(14, 32), 256, 0, stream>>>(Dt, wb, Bm);
    so3_gemm_all<<<1896, 256, 0, stream>>>((const __bf16*)A, Bm, out);
}

// Round 2
// 392.438 us; speedup vs baseline: 1.0538x; 1.0075x over previous
//
#include <hip/hip_runtime.h>
#include <hip/hip_bf16.h>

#define IDIM 1771
#define NF 64
#define NG 512

constexpr int OFFS[12] = {0, 1, 10, 35, 84, 165, 286, 455, 680, 969, 1330, 1771};

typedef float f32x4 __attribute__((ext_vector_type(4)));
typedef float f32x2 __attribute__((ext_vector_type(2)));
typedef __bf16 bf16x2 __attribute__((ext_vector_type(2)));
typedef __bf16 bf16x8 __attribute__((ext_vector_type(8)));

__device__ __forceinline__ void gl_lds16(const void* g, void* l) {
    __builtin_amdgcn_global_load_lds((const __attribute__((address_space(1))) void*)g,
                                     (__attribute__((address_space(3))) void*)l, 16, 0, 0);
}

// ---------------------------------------------------------------------------
// Fused prep + repack_x. All global-load phases now batch 16 independent
// loads into registers BEFORE any dependent LDS write (explicit MLP; the
// compiler was chaining load->wait->write per element).
// ---------------------------------------------------------------------------
__global__ __launch_bounds__(256) void prep_repack_kernel(const float* __restrict__ D,
                                                          const float* __restrict__ w,
                                                          const float* __restrict__ x,
                                                          __bf16* __restrict__ Dt,
                                                          __bf16* __restrict__ wb,
                                                          __hip_bfloat16* __restrict__ A) {
    __shared__ alignas(16) char smem[16640];
    const int blk = blockIdx.x;
    const int t = threadIdx.x;
    const int lane = t & 63, grp = t >> 6;

    if (blk < 224) {
        // D transpose (512,1771) f32 -> Dt (1771,512) bf16
        float (*T)[65] = (float (*)[65])smem;
        const int ct = blk >> 3, nt = blk & 7;
        const int c0 = ct * 64, n0 = nt * 64;
        float tmp[16];
#pragma unroll
        for (int p = 0; p < 16; ++p) {
            int nn = grp + p * 4;
            int c = c0 + lane;
            tmp[p] = (c < IDIM) ? D[(size_t)(n0 + nn) * IDIM + c] : 0.0f;
        }
#pragma unroll
        for (int p = 0; p < 16; ++p) T[grp + p * 4][lane] = tmp[p];
        __syncthreads();
        for (int cc = grp; cc < 64; cc += 4) {
            int c = c0 + cc;
            if (c < IDIM) Dt[c * NG + n0 + lane] = (__bf16)T[lane][cc];
        }
    } else if (blk < 288) {
        // w transpose-cast: wb[o][i][n] = bf16(w[i][o][n]); batch 8 loads
        const int o = blk - 224;
#pragma unroll
        for (int ii0 = 0; ii0 < 64; ii0 += 8) {
            f32x2 tmp[8];
#pragma unroll
            for (int j = 0; j < 8; ++j)
                tmp[j] = *(const f32x2*)&w[((size_t)((ii0 + j) * 64 + o)) * NG + t * 2];
#pragma unroll
            for (int j = 0; j < 8; ++j) {
                bf16x2 ov;
                ov.x = (__bf16)tmp[j].x;
                ov.y = (__bf16)tmp[j].y;
                *(bf16x2*)&wb[((size_t)(o * 64 + ii0 + j)) * NG + t * 2] = ov;
            }
        }
    } else {
        // repack x: A[m][u*64+i] = bf16(x[b][i][off+u*d+m])
        const int idx = blk - 288;
        const int l = idx >> 8;        // 0..10
        const int b = idx & 255;       // 0..255
        const int d = 2 * l + 1, off = OFFS[l], csq = d * d, Kp = 64 * d;
        __bf16 (*T)[66] = (__bf16 (*)[66])smem;  // [i=64][c=66 padded]
        const float* xb = x + (size_t)b * NF * IDIM + off;
        __bf16* Ab = (__bf16*)(A + (size_t)16384 * off + (size_t)b * d * Kp);

        for (int c0 = 0; c0 < csq; c0 += 64) {
            // phase 1: 16 independent coalesced f32 loads, then LDS fill
            float tmp[16];
#pragma unroll
            for (int p = 0; p < 16; ++p) {
                int ii = grp + p * 4;
                int c = c0 + lane;
                tmp[p] = (c < csq) ? xb[(size_t)ii * IDIM + c] : 0.0f;
            }
#pragma unroll
            for (int p = 0; p < 16; ++p) T[grp + p * 4][lane] = (__bf16)tmp[p];
            __syncthreads();
            // phase 2: per-thread gather 8 i's for one c -> one 16B store
#pragma unroll
            for (int s = 0; s < 2; ++s) {
                int idx2 = s * 256 + t;
                int c_loc = idx2 >> 3, i0 = (idx2 & 7) * 8;
                int c = c0 + c_loc;
                if (c < csq) {
                    int u = (unsigned)c / (unsigned)d;
                    int m = c - u * d;
                    bf16x8 v;
#pragma unroll
                    for (int j = 0; j < 8; ++j) v[j] = T[i0 + j][c_loc];
                    *(bf16x8*)(Ab + (size_t)m * Kp + u * 64 + i0) = v;
                }
            }
            __syncthreads();
        }
    }
}

// ---------------------------------------------------------------------------
// psi GEMM (MFMA): 3-buffer, 2-deep prefetch, counted vmcnt(4) (never drain
// the in-flight younger stage). Issue->use distance = 2 compute phases.
// ---------------------------------------------------------------------------
__global__ __launch_bounds__(256) void psi_mfma_kernel(const __bf16* __restrict__ Dt,
                                                       const __bf16* __restrict__ wb,
                                                       __bf16* __restrict__ Bm) {
    __shared__ alignas(16) __bf16 S[3 * 8192];  // 3 stages x (As 4096 | Bs 4096)

    const int t = threadIdx.x, w = t >> 6, ln = t & 63;
    const int row0 = blockIdx.x * 128;  // c
    const int col0 = blockIdx.y * 128;  // io'

    const __bf16* gp[4];
    __bf16* lp[4];
#pragma unroll
    for (int q = 0; q < 4; ++q) {
        int chunk = w * 4 + q;
        bool isA = chunk < 8;
        int j = chunk & 7;
        int r16 = j * 16 + (ln >> 2);
        int g = isA ? (row0 + r16 < IDIM ? row0 + r16 : IDIM - 1) : (col0 + r16);
        gp[q] = (isA ? Dt : wb) + (size_t)g * NG + (ln & 3) * 8;
        lp[q] = S + (isA ? 0 : 4096) + j * 512;
    }

    f32x4 acc[4][4];
    f32x4 zero = {0.0f, 0.0f, 0.0f, 0.0f};
#pragma unroll
    for (int i = 0; i < 4; ++i)
#pragma unroll
        for (int j = 0; j < 4; ++j) acc[i][j] = zero;

    const int wr = (w >> 1) * 64, wc = (w & 1) * 64;
    const int fr = ln & 15, kh = ln >> 4;

    auto STAGE = [&](int bi) {
#pragma unroll
        for (int q = 0; q < 4; ++q) {
            gl_lds16(gp[q], lp[q] + bi * 8192);
            gp[q] += 32;
        }
    };

    const int nsteps = NG / 32;  // 16
    STAGE(0);
    STAGE(1);

    int bi = 0;
    for (int s = 0; s < nsteps; ++s) {
        if (s + 1 < nsteps) asm volatile("s_waitcnt vmcnt(4)" ::: "memory");
        else                asm volatile("s_waitcnt vmcnt(0)" ::: "memory");
        __builtin_amdgcn_s_barrier();
        __builtin_amdgcn_sched_barrier(0);
        if (s + 2 < nsteps) {
            int nb = s + 2 - ((s + 2) >= 3 ? 3 : 0);
            nb = (s + 2) % 3;
            STAGE(nb);
        }
        __builtin_amdgcn_sched_barrier(0);
        const __bf16* As_ = S + bi * 8192;
        const __bf16* Bs_ = S + bi * 8192 + 4096;
        bf16x8 af[4], bfr[4];
#pragma unroll
        for (int mt = 0; mt < 4; ++mt)
            af[mt] = *(const bf16x8*)&As_[(wr + mt * 16 + fr) * 32 + kh * 8];
#pragma unroll
        for (int nt = 0; nt < 4; ++nt)
            bfr[nt] = *(const bf16x8*)&Bs_[(wc + nt * 16 + fr) * 32 + kh * 8];
#pragma unroll
        for (int mt = 0; mt < 4; ++mt)
#pragma unroll
            for (int nt = 0; nt < 4; ++nt)
                acc[mt][nt] = __builtin_amdgcn_mfma_f32_16x16x32_bf16(af[mt], bfr[nt],
                                                                      acc[mt][nt], 0, 0, 0);
        bi = (bi == 2) ? 0 : bi + 1;
    }

    const float sc = 0.04419417382415922f;  // 1/sqrt(512)
    const int o = (col0 + wc) >> 6;         // wave-uniform
#pragma unroll
    for (int mt = 0; mt < 4; ++mt) {
#pragma unroll
        for (int e = 0; e < 4; ++e) {
            int c = row0 + wr + mt * 16 + kh * 4 + e;
            if (c < IDIM) {
                int l = 0;
#pragma unroll
                for (int ll = 1; ll < 11; ++ll)
                    if (c >= OFFS[ll]) l = ll;
                int d = 2 * l + 1, off = OFFS[l];
                int rem = c - off;
                int u = (unsigned)rem / (unsigned)d;
                int v = rem - u * d;
                __bf16* bb = Bm + (size_t)4096 * off + (size_t)(o * d + v) * (64 * d) + u * 64;
#pragma unroll
                for (int nt = 0; nt < 4; ++nt) {
                    int i = nt * 16 + fr;  // consecutive across 16-lane group
                    bb[i] = (__bf16)(acc[mt][nt][e] * sc);
                }
            }
        }
    }
}

// ---------------------------------------------------------------------------
// Merged stage-2 GEMM, XCD-swizzled, 3-buffer 2-deep prefetch, counted vmcnt.
// ---------------------------------------------------------------------------
__global__ __launch_bounds__(256) void so3_gemm_all(const __bf16* __restrict__ A,
                                                    const __bf16* __restrict__ Bm,
                                                    float* __restrict__ out) {
    const int bid = blockIdx.x;
    const int v_ = (bid & 7) * 237 + (bid >> 3);  // grid 1896 = 8*237
    if (v_ >= 1892) return;

    int l = 10, base = 0;
    if (v_ >= 462)  { l = 9; base = 462; }
    if (v_ >= 842)  { l = 8; base = 842; }
    if (v_ >= 1148) { l = 7; base = 1148; }
    if (v_ >= 1388) { l = 6; base = 1388; }
    if (v_ >= 1570) { l = 5; base = 1570; }
    if (v_ >= 1702) { l = 4; base = 1702; }
    if (v_ >= 1792) { l = 3; base = 1792; }
    if (v_ >= 1848) { l = 2; base = 1848; }
    if (v_ >= 1878) { l = 1; base = 1878; }
    if (v_ >= 1890) { l = 0; base = 1890; }

    const int d = 2 * l + 1;
    const int off = OFFS[l];
    const int Np = 64 * d, Kp = 64 * d;
    const int ntiles = l + 1;
    const int rel = v_ - base;
    const int bx = (unsigned)rel / (unsigned)ntiles;
    const int by = rel - bx * ntiles;
    const int row0 = bx * 128, col0 = by * 128;

    constexpr float ALPHA[11] = {0.125f, 0.07216878f, 0.05590170f, 0.04724556f,
                                 0.04166667f, 0.03768892f, 0.03466879f, 0.03227486f,
                                 0.03031695f, 0.02867697f, 0.02727724f};

    __shared__ alignas(16) __bf16 S[3 * 8192];  // 3 stages x (As | Bs)

    const int t = threadIdx.x, w = t >> 6, ln = t & 63;

    const __bf16* Abase = A + (size_t)16384 * off;
    const __bf16* Bbase = Bm + (size_t)4096 * off;

    const __bf16* gp[4];
    __bf16* lp[4];
#pragma unroll
    for (int q = 0; q < 4; ++q) {
        int chunk = w * 4 + q;
        bool isA = chunk < 8;
        int j = chunk & 7;
        int r16 = j * 16 + (ln >> 2);
        int g = isA ? (row0 + r16) : (col0 + r16 < Np ? col0 + r16 : Np - 1);
        gp[q] = (isA ? Abase : Bbase) + (size_t)g * Kp + (ln & 3) * 8;
        lp[q] = S + (isA ? 0 : 4096) + j * 512;
    }

    f32x4 acc[4][4];
    f32x4 zero = {0.0f, 0.0f, 0.0f, 0.0f};
#pragma unroll
    for (int i = 0; i < 4; ++i)
#pragma unroll
        for (int j = 0; j < 4; ++j) acc[i][j] = zero;

    const int wr = (w >> 1) * 64, wc = (w & 1) * 64;
    const int fr = ln & 15, kh = ln >> 4;

    auto STAGE = [&](int bi) {
#pragma unroll
        for (int q = 0; q < 4; ++q) {
            gl_lds16(gp[q], lp[q] + bi * 8192);
            gp[q] += 32;
        }
    };

    const int nsteps = Kp / 32;  // 2..42 (even for l=0)
    STAGE(0);
    STAGE(1);

    int bi = 0;
    for (int s = 0; s < nsteps; ++s) {
        if (s + 1 < nsteps) asm volatile("s_waitcnt vmcnt(4)" ::: "memory");
        else                asm volatile("s_waitcnt vmcnt(0)" ::: "memory");
        __builtin_amdgcn_s_barrier();
        __builtin_amdgcn_sched_barrier(0);
        if (s + 2 < nsteps) STAGE((s + 2) % 3);
        __builtin_amdgcn_sched_barrier(0);
        const __bf16* As_ = S + bi * 8192;
        const __bf16* Bs_ = S + bi * 8192 + 4096;
        bf16x8 af[4], bfr[4];
#pragma unroll
        for (int mt = 0; mt < 4; ++mt)
            af[mt] = *(const bf16x8*)&As_[(wr + mt * 16 + fr) * 32 + kh * 8];
#pragma unroll
        for (int nt = 0; nt < 4; ++nt)
            bfr[nt] = *(const bf16x8*)&Bs_[(wc + nt * 16 + fr) * 32 + kh * 8];
#pragma unroll
        for (int mt = 0; mt < 4; ++mt)
#pragma unroll
            for (int nt = 0; nt < 4; ++nt)
                acc[mt][nt] = __builtin_amdgcn_mfma_f32_16x16x32_bf16(af[mt], bfr[nt],
                                                                      acc[mt][nt], 0, 0, 0);
        bi = (bi == 2) ? 0 : bi + 1;
    }

    // ---- epilogue: per-wave LDS reorder so stores run contiguous along m ----
    __syncthreads();  // all waves done with LDS before we reuse it
    float* Tw = (float*)S + w * 256;  // 16x16 f32 per wave (1KB)
    const float alpha = ALPHA[l];

#pragma unroll
    for (int mt = 0; mt < 4; ++mt) {
        // this lane's store row: r = row0+wr+mt*16+fr (contiguous across fr)
        int r = row0 + wr + mt * 16 + fr;
        int b = (unsigned)r / (unsigned)d;
        int m = r - b * d;
        float* ob = out + (size_t)b * NF * IDIM + off + m;
#pragma unroll
        for (int nt = 0; nt < 4; ++nt) {
            // write C subtile (row=kh*4+e, col=fr) into Tw[row][col]
#pragma unroll
            for (int e = 0; e < 4; ++e) Tw[(kh * 4 + e) * 16 + fr] = acc[mt][nt][e];
            // read back transposed: lane handles (row=fr, cols kh*4..kh*4+3)
            f32x4 vals = *(const f32x4*)&Tw[fr * 16 + kh * 4];
            int qb = col0 + wc + nt * 16 + kh * 4;
            int o = (unsigned)qb / (unsigned)d;
            int vv = qb - o * d;
#pragma unroll
            for (int j = 0; j < 4; ++j) {
                if (qb + j < Np) ob[o * IDIM + vv * d] = alpha * vals[j];
                ++vv;
                if (vv == d) { vv = 0; ++o; }
            }
        }
    }
}

// ---------------------------------------------------------------------------
extern "C" void kernel_launch(void* const* d_in, const int* in_sizes, int n_in,
                              void* d_out, int out_size, void* d_ws, size_t ws_size,
                              hipStream_t stream) {
    const float* x = (const float*)d_in[0];   // (256, 64, 1771)
    const float* D = (const float*)d_in[1];   // (512, 1771)
    const float* w = (const float*)d_in[2];   // (64, 64, 512)
    float* out = (float*)d_out;               // (256, 64, 1771)

    char* ws = (char*)d_ws;
    const size_t DT_BYTES = (size_t)IDIM * NG * 2;        // 1,813,504
    const size_t WB_BYTES = (size_t)4096 * NG * 2;        // 4,194,304
    const size_t A_BYTES = (size_t)16384 * IDIM * 2;      // 58,032,128

    __bf16* Dt = (__bf16*)ws;
    __bf16* wb = (__bf16*)(ws + DT_BYTES);
    __hip_bfloat16* A = (__hip_bfloat16*)(ws + DT_BYTES + WB_BYTES);
    __bf16* Bm = (__bf16*)(ws + DT_BYTES + WB_BYTES + A_BYTES);

    prep_repack_kernel<<<3104, 256, 0, stream>>>(D, w, x, Dt, wb, A);
    psi_mfma_kernel<<<dim3(14, 32), 256, 0, stream>>>(Dt, wb, Bm);
    so3_gemm_all<<<1896, 256, 0, stream>>>((const __bf16*)A, Bm, out);
}

// Round 3
// 379.529 us; speedup vs baseline: 1.0896x; 1.0340x over previous
//
#include <hip/hip_runtime.h>
#include <hip/hip_bf16.h>

#define IDIM 1771
#define NF 64
#define NG 512

constexpr int OFFS[12] = {0, 1, 10, 35, 84, 165, 286, 455, 680, 969, 1330, 1771};

typedef float f32x4 __attribute__((ext_vector_type(4)));
typedef float f32x2 __attribute__((ext_vector_type(2)));
typedef __bf16 bf16x2 __attribute__((ext_vector_type(2)));
typedef __bf16 bf16x8 __attribute__((ext_vector_type(8)));

__device__ __forceinline__ void gl_lds16(const void* g, void* l) {
    __builtin_amdgcn_global_load_lds((const __attribute__((address_space(1))) void*)g,
                                     (__attribute__((address_space(3))) void*)l, 16, 0, 0);
}

// ---------------------------------------------------------------------------
// prep_dw: blk 0..223 transpose D -> Dt bf16; blk 224..287 w -> wb bf16.
// Split from repack_x so rocprof shows each kernel's true duration.
// ---------------------------------------------------------------------------
__global__ __launch_bounds__(256) void prep_dw_kernel(const float* __restrict__ D,
                                                      const float* __restrict__ w,
                                                      __bf16* __restrict__ Dt,
                                                      __bf16* __restrict__ wb) {
    __shared__ alignas(16) float T[64][65];
    const int blk = blockIdx.x;
    const int t = threadIdx.x;
    const int lane = t & 63, grp = t >> 6;

    if (blk < 224) {
        const int ct = blk >> 3, nt = blk & 7;
        const int c0 = ct * 64, n0 = nt * 64;
        float tmp[16];
#pragma unroll
        for (int p = 0; p < 16; ++p) {
            int nn = grp + p * 4;
            int c = c0 + lane;
            tmp[p] = (c < IDIM) ? D[(size_t)(n0 + nn) * IDIM + c] : 0.0f;
        }
#pragma unroll
        for (int p = 0; p < 16; ++p) T[grp + p * 4][lane] = tmp[p];
        __syncthreads();
        for (int cc = grp; cc < 64; cc += 4) {
            int c = c0 + cc;
            if (c < IDIM) Dt[c * NG + n0 + lane] = (__bf16)T[lane][cc];
        }
    } else {
        const int o = blk - 224;
#pragma unroll
        for (int ii0 = 0; ii0 < 64; ii0 += 8) {
            f32x2 tmp[8];
#pragma unroll
            for (int j = 0; j < 8; ++j)
                tmp[j] = *(const f32x2*)&w[((size_t)((ii0 + j) * 64 + o)) * NG + t * 2];
#pragma unroll
            for (int j = 0; j < 8; ++j) {
                bf16x2 ov;
                ov.x = (__bf16)tmp[j].x;
                ov.y = (__bf16)tmp[j].y;
                *(bf16x2*)&wb[((size_t)(o * 64 + ii0 + j)) * NG + t * 2] = ov;
            }
        }
    }
}

// ---------------------------------------------------------------------------
// repack_x: A[m][u*64+i] = bf16(x[b][i][off+u*d+m]), one block per (l,b).
// ---------------------------------------------------------------------------
__global__ __launch_bounds__(256) void repack_x_kernel(const float* __restrict__ x,
                                                       __hip_bfloat16* __restrict__ A) {
    __shared__ alignas(16) __bf16 T[64][66];
    const int idx = blockIdx.x;
    const int l = idx >> 8;        // 0..10
    const int b = idx & 255;       // 0..255
    const int t = threadIdx.x;
    const int lane = t & 63, grp = t >> 6;
    const int d = 2 * l + 1, off = OFFS[l], csq = d * d, Kp = 64 * d;
    const float* xb = x + (size_t)b * NF * IDIM + off;
    __bf16* Ab = (__bf16*)(A + (size_t)16384 * off + (size_t)b * d * Kp);

    for (int c0 = 0; c0 < csq; c0 += 64) {
        float tmp[16];
#pragma unroll
        for (int p = 0; p < 16; ++p) {
            int ii = grp + p * 4;
            int c = c0 + lane;
            tmp[p] = (c < csq) ? xb[(size_t)ii * IDIM + c] : 0.0f;
        }
#pragma unroll
        for (int p = 0; p < 16; ++p) T[grp + p * 4][lane] = (__bf16)tmp[p];
        __syncthreads();
#pragma unroll
        for (int s = 0; s < 2; ++s) {
            int idx2 = s * 256 + t;
            int c_loc = idx2 >> 3, i0 = (idx2 & 7) * 8;
            int c = c0 + c_loc;
            if (c < csq) {
                int u = (unsigned)c / (unsigned)d;
                int m = c - u * d;
                bf16x8 v;
#pragma unroll
                for (int j = 0; j < 8; ++j) v[j] = T[i0 + j][c_loc];
                *(bf16x8*)(Ab + (size_t)m * Kp + u * 64 + i0) = v;
            }
        }
        __syncthreads();
    }
}

// ---------------------------------------------------------------------------
// psi GEMM: BK=64 fat phases, 2-stage dbuf, min-2-phase schedule
// (STAGE(next) -> ds_read(cur)+MFMA -> vmcnt(0)+barrier). LDS rows are 128B,
// so slots are XOR-swizzled: phys_slot = log_slot ^ (row&7); gl_lds dest stays
// linear, the *global source* address carries the swizzle (per-lane).
// ---------------------------------------------------------------------------
__global__ __launch_bounds__(256) void psi_mfma_kernel(const __bf16* __restrict__ Dt,
                                                       const __bf16* __restrict__ wb,
                                                       __bf16* __restrict__ Bm) {
    __shared__ alignas(16) __bf16 S[2 * 16384];  // 64KB: stage x (A 8192 | B 8192)

    const int t = threadIdx.x, w = t >> 6, ln = t & 63;
    const int row0 = blockIdx.x * 128;  // c
    const int col0 = blockIdx.y * 128;  // io'

    const bool isA = (w < 2);
    const int wsub = w & 1;
    const int rowloc = ln >> 3;             // 0..7
    const int logslot = (ln & 7) ^ rowloc;  // swizzled source k-slot

    const __bf16* gp[8];
    __bf16* lp[8];
#pragma unroll
    for (int q = 0; q < 8; ++q) {
        int chunk = wsub * 8 + q;           // 0..15
        int row = chunk * 8 + rowloc;       // 0..127
        int g = isA ? (row0 + row < IDIM ? row0 + row : IDIM - 1) : (col0 + row);
        gp[q] = (isA ? Dt : wb) + (size_t)g * NG + logslot * 8;
        lp[q] = S + (isA ? 0 : 8192) + chunk * 512;
    }

    f32x4 acc[4][4];
    f32x4 zero = {0.0f, 0.0f, 0.0f, 0.0f};
#pragma unroll
    for (int i = 0; i < 4; ++i)
#pragma unroll
        for (int j = 0; j < 4; ++j) acc[i][j] = zero;

    const int wr = (w >> 1) * 64, wc = (w & 1) * 64;
    const int fr = ln & 15, kh = ln >> 4;
    const int fx = fr & 7;

    int aoff[2][4], boff[2][4];
#pragma unroll
    for (int kk = 0; kk < 2; ++kk)
#pragma unroll
        for (int mt = 0; mt < 4; ++mt) {
            aoff[kk][mt] = (wr + mt * 16 + fr) * 64 + (((kk << 2) | kh) ^ fx) * 8;
            boff[kk][mt] = (wc + mt * 16 + fr) * 64 + (((kk << 2) | kh) ^ fx) * 8;
        }

    const int np = NG / 64;  // 8

    // prologue
#pragma unroll
    for (int q = 0; q < 8; ++q) { gl_lds16(gp[q], lp[q]); gp[q] += 64; }
    asm volatile("s_waitcnt vmcnt(0)" ::: "memory");
    __builtin_amdgcn_s_barrier();
    __builtin_amdgcn_sched_barrier(0);

    int bi = 0;
    for (int p = 0; p < np; ++p) {
        if (p + 1 < np) {
#pragma unroll
            for (int q = 0; q < 8; ++q) {
                gl_lds16(gp[q], lp[q] + (bi ^ 1) * 16384);
                gp[q] += 64;
            }
        }
        const __bf16* As_ = S + bi * 16384;
        const __bf16* Bs_ = As_ + 8192;
        bf16x8 af[2][4], bf_[2][4];
#pragma unroll
        for (int kk = 0; kk < 2; ++kk) {
#pragma unroll
            for (int mt = 0; mt < 4; ++mt) af[kk][mt] = *(const bf16x8*)&As_[aoff[kk][mt]];
#pragma unroll
            for (int nt = 0; nt < 4; ++nt) bf_[kk][nt] = *(const bf16x8*)&Bs_[boff[kk][nt]];
        }
#pragma unroll
        for (int kk = 0; kk < 2; ++kk)
#pragma unroll
            for (int mt = 0; mt < 4; ++mt)
#pragma unroll
                for (int nt = 0; nt < 4; ++nt)
                    acc[mt][nt] = __builtin_amdgcn_mfma_f32_16x16x32_bf16(
                        af[kk][mt], bf_[kk][nt], acc[mt][nt], 0, 0, 0);
        asm volatile("s_waitcnt vmcnt(0)" ::: "memory");
        __builtin_amdgcn_s_barrier();
        __builtin_amdgcn_sched_barrier(0);
        bi ^= 1;
    }

    const float sc = 0.04419417382415922f;  // 1/sqrt(512)
    const int o = (col0 + wc) >> 6;         // wave-uniform
#pragma unroll
    for (int mt = 0; mt < 4; ++mt) {
#pragma unroll
        for (int e = 0; e < 4; ++e) {
            int c = row0 + wr + mt * 16 + kh * 4 + e;
            if (c < IDIM) {
                int l = 0;
#pragma unroll
                for (int ll = 1; ll < 11; ++ll)
                    if (c >= OFFS[ll]) l = ll;
                int d = 2 * l + 1, off = OFFS[l];
                int rem = c - off;
                int u = (unsigned)rem / (unsigned)d;
                int v = rem - u * d;
                __bf16* bb = Bm + (size_t)4096 * off + (size_t)(o * d + v) * (64 * d) + u * 64;
#pragma unroll
                for (int nt = 0; nt < 4; ++nt) {
                    int i = nt * 16 + fr;
                    bb[i] = (__bf16)(acc[mt][nt][e] * sc);
                }
            }
        }
    }
}

// ---------------------------------------------------------------------------
// Merged stage-2 GEMM: same BK=64 min-2-phase structure + XOR slot swizzle.
// ---------------------------------------------------------------------------
__global__ __launch_bounds__(256) void so3_gemm_all(const __bf16* __restrict__ A,
                                                    const __bf16* __restrict__ Bm,
                                                    float* __restrict__ out) {
    const int bid = blockIdx.x;
    const int v_ = (bid & 7) * 237 + (bid >> 3);  // grid 1896 = 8*237
    if (v_ >= 1892) return;

    int l = 10, base = 0;
    if (v_ >= 462)  { l = 9; base = 462; }
    if (v_ >= 842)  { l = 8; base = 842; }
    if (v_ >= 1148) { l = 7; base = 1148; }
    if (v_ >= 1388) { l = 6; base = 1388; }
    if (v_ >= 1570) { l = 5; base = 1570; }
    if (v_ >= 1702) { l = 4; base = 1702; }
    if (v_ >= 1792) { l = 3; base = 1792; }
    if (v_ >= 1848) { l = 2; base = 1848; }
    if (v_ >= 1878) { l = 1; base = 1878; }
    if (v_ >= 1890) { l = 0; base = 1890; }

    const int d = 2 * l + 1;
    const int off = OFFS[l];
    const int Np = 64 * d, Kp = 64 * d;
    const int ntiles = l + 1;
    const int rel = v_ - base;
    const int bx = (unsigned)rel / (unsigned)ntiles;
    const int by = rel - bx * ntiles;
    const int row0 = bx * 128, col0 = by * 128;

    constexpr float ALPHA[11] = {0.125f, 0.07216878f, 0.05590170f, 0.04724556f,
                                 0.04166667f, 0.03768892f, 0.03466879f, 0.03227486f,
                                 0.03031695f, 0.02867697f, 0.02727724f};

    __shared__ alignas(16) __bf16 S[2 * 16384];  // 64KB

    const int t = threadIdx.x, w = t >> 6, ln = t & 63;

    const __bf16* Abase = A + (size_t)16384 * off;
    const __bf16* Bbase = Bm + (size_t)4096 * off;

    const bool isA = (w < 2);
    const int wsub = w & 1;
    const int rowloc = ln >> 3;
    const int logslot = (ln & 7) ^ rowloc;

    const __bf16* gp[8];
    __bf16* lp[8];
#pragma unroll
    for (int q = 0; q < 8; ++q) {
        int chunk = wsub * 8 + q;
        int row = chunk * 8 + rowloc;
        int g = isA ? (row0 + row) : (col0 + row < Np ? col0 + row : Np - 1);
        gp[q] = (isA ? Abase : Bbase) + (size_t)g * Kp + logslot * 8;
        lp[q] = S + (isA ? 0 : 8192) + chunk * 512;
    }

    f32x4 acc[4][4];
    f32x4 zero = {0.0f, 0.0f, 0.0f, 0.0f};
#pragma unroll
    for (int i = 0; i < 4; ++i)
#pragma unroll
        for (int j = 0; j < 4; ++j) acc[i][j] = zero;

    const int wr = (w >> 1) * 64, wc = (w & 1) * 64;
    const int fr = ln & 15, kh = ln >> 4;
    const int fx = fr & 7;

    int aoff[2][4], boff[2][4];
#pragma unroll
    for (int kk = 0; kk < 2; ++kk)
#pragma unroll
        for (int mt = 0; mt < 4; ++mt) {
            aoff[kk][mt] = (wr + mt * 16 + fr) * 64 + (((kk << 2) | kh) ^ fx) * 8;
            boff[kk][mt] = (wc + mt * 16 + fr) * 64 + (((kk << 2) | kh) ^ fx) * 8;
        }

    const int np = Kp / 64;  // = d (1..21)

    // prologue
#pragma unroll
    for (int q = 0; q < 8; ++q) { gl_lds16(gp[q], lp[q]); gp[q] += 64; }
    asm volatile("s_waitcnt vmcnt(0)" ::: "memory");
    __builtin_amdgcn_s_barrier();
    __builtin_amdgcn_sched_barrier(0);

    int bi = 0;
    for (int p = 0; p < np; ++p) {
        if (p + 1 < np) {
#pragma unroll
            for (int q = 0; q < 8; ++q) {
                gl_lds16(gp[q], lp[q] + (bi ^ 1) * 16384);
                gp[q] += 64;
            }
        }
        const __bf16* As_ = S + bi * 16384;
        const __bf16* Bs_ = As_ + 8192;
        bf16x8 af[2][4], bf_[2][4];
#pragma unroll
        for (int kk = 0; kk < 2; ++kk) {
#pragma unroll
            for (int mt = 0; mt < 4; ++mt) af[kk][mt] = *(const bf16x8*)&As_[aoff[kk][mt]];
#pragma unroll
            for (int nt = 0; nt < 4; ++nt) bf_[kk][nt] = *(const bf16x8*)&Bs_[boff[kk][nt]];
        }
#pragma unroll
        for (int kk = 0; kk < 2; ++kk)
#pragma unroll
            for (int mt = 0; mt < 4; ++mt)
#pragma unroll
                for (int nt = 0; nt < 4; ++nt)
                    acc[mt][nt] = __builtin_amdgcn_mfma_f32_16x16x32_bf16(
                        af[kk][mt], bf_[kk][nt], acc[mt][nt], 0, 0, 0);
        asm volatile("s_waitcnt vmcnt(0)" ::: "memory");
        __builtin_amdgcn_s_barrier();
        __builtin_amdgcn_sched_barrier(0);
        bi ^= 1;
    }

    // ---- epilogue: per-wave LDS reorder so stores run contiguous along m ----
    __syncthreads();
    float* Tw = (float*)S + w * 256;  // 16x16 f32 per wave (1KB)
    const float alpha = ALPHA[l];

#pragma unroll
    for (int mt = 0; mt < 4; ++mt) {
        int r = row0 + wr + mt * 16 + fr;
        int b = (unsigned)r / (unsigned)d;
        int m = r - b * d;
        float* ob = out + (size_t)b * NF * IDIM + off + m;
#pragma unroll
        for (int nt = 0; nt < 4; ++nt) {
#pragma unroll
            for (int e = 0; e < 4; ++e) Tw[(kh * 4 + e) * 16 + fr] = acc[mt][nt][e];
            f32x4 vals = *(const f32x4*)&Tw[fr * 16 + kh * 4];
            int qb = col0 + wc + nt * 16 + kh * 4;
            int o = (unsigned)qb / (unsigned)d;
            int vv = qb - o * d;
#pragma unroll
            for (int j = 0; j < 4; ++j) {
                if (qb + j < Np) ob[o * IDIM + vv * d] = alpha * vals[j];
                ++vv;
                if (vv == d) { vv = 0; ++o; }
            }
        }
    }
}

// ---------------------------------------------------------------------------
extern "C" void kernel_launch(void* const* d_in, const int* in_sizes, int n_in,
                              void* d_out, int out_size, void* d_ws, size_t ws_size,
                              hipStream_t stream) {
    const float* x = (const float*)d_in[0];   // (256, 64, 1771)
    const float* D = (const float*)d_in[1];   // (512, 1771)
    const float* w = (const float*)d_in[2];   // (64, 64, 512)
    float* out = (float*)d_out;               // (256, 64, 1771)

    char* ws = (char*)d_ws;
    const size_t DT_BYTES = (size_t)IDIM * NG * 2;        // 1,813,504
    const size_t WB_BYTES = (size_t)4096 * NG * 2;        // 4,194,304
    const size_t A_BYTES = (size_t)16384 * IDIM * 2;      // 58,032,128

    __bf16* Dt = (__bf16*)ws;
    __bf16* wb = (__bf16*)(ws + DT_BYTES);
    __hip_bfloat16* A = (__hip_bfloat16*)(ws + DT_BYTES + WB_BYTES);
    __bf16* Bm = (__bf16*)(ws + DT_BYTES + WB_BYTES + A_BYTES);

    prep_dw_kernel<<<288, 256, 0, stream>>>(D, w, Dt, wb);
    repack_x_kernel<<<2816, 256, 0, stream>>>(x, A);
    psi_mfma_kernel<<<dim3(14, 32), 256, 0, stream>>>(Dt, wb, Bm);
    so3_gemm_all<<<1896, 256, 0, stream>>>((const __bf16*)A, Bm, out);
}